// Round 3
// baseline (283.950 us; speedup 1.0000x reference)
//
#include <hip/hip_runtime.h>

#define DD 4096
#define SS 8192
#define RPW 4                     // rows per wave
#define WPB 4                     // waves per block (256 threads)
// total waves = 2*SS / RPW = 4096 -> grid = 1024 blocks

__global__ __launch_bounds__(256) void gemv_kernel(
    const float* __restrict__ G1, const float* __restrict__ G2,
    const float* __restrict__ wp1, const float* __restrict__ wp2,
    float* __restrict__ logits)
{
    const int wid  = threadIdx.x >> 6;
    const int lane = threadIdx.x & 63;
    const int g    = blockIdx.x * WPB + wid;      // global wave id, 0..4095

    const int HALF = (2 * SS / RPW) / 2;          // 2048 waves per matrix
    const float* G;
    const float* w;
    int row0, obase;
    if (g < HALF) { G = G1; w = wp1; row0 = g * RPW;          obase = 0;  }
    else          { G = G2; w = wp2; row0 = (g - HALF) * RPW; obase = SS; }

    const float4* __restrict__ W4 = reinterpret_cast<const float4*>(w);

    // Hoist the per-lane wp slice into registers: 16 float4 = the whole
    // 16 KiB wp row spread across 64 lanes. Never re-read from memory.
    float4 wr[16];
    #pragma unroll
    for (int i = 0; i < 16; ++i)
        wr[i] = W4[i * 64 + lane];

    #pragma unroll
    for (int r = 0; r < RPW; ++r) {
        const float4* __restrict__ Grow =
            reinterpret_cast<const float4*>(G + (size_t)(row0 + r) * DD);

        float a0 = 0.f, a1 = 0.f, a2 = 0.f, a3 = 0.f;
        #pragma unroll
        for (int i = 0; i < 16; i += 4) {
            float4 x0 = Grow[(i + 0) * 64 + lane];
            float4 x1 = Grow[(i + 1) * 64 + lane];
            float4 x2 = Grow[(i + 2) * 64 + lane];
            float4 x3 = Grow[(i + 3) * 64 + lane];
            a0 = fmaf(x0.x, wr[i+0].x, a0); a0 = fmaf(x0.y, wr[i+0].y, a0);
            a0 = fmaf(x0.z, wr[i+0].z, a0); a0 = fmaf(x0.w, wr[i+0].w, a0);
            a1 = fmaf(x1.x, wr[i+1].x, a1); a1 = fmaf(x1.y, wr[i+1].y, a1);
            a1 = fmaf(x1.z, wr[i+1].z, a1); a1 = fmaf(x1.w, wr[i+1].w, a1);
            a2 = fmaf(x2.x, wr[i+2].x, a2); a2 = fmaf(x2.y, wr[i+2].y, a2);
            a2 = fmaf(x2.z, wr[i+2].z, a2); a2 = fmaf(x2.w, wr[i+2].w, a2);
            a3 = fmaf(x3.x, wr[i+3].x, a3); a3 = fmaf(x3.y, wr[i+3].y, a3);
            a3 = fmaf(x3.z, wr[i+3].z, a3); a3 = fmaf(x3.w, wr[i+3].w, a3);
        }
        float acc = (a0 + a1) + (a2 + a3);

        // 64-lane butterfly reduce
        #pragma unroll
        for (int off = 32; off > 0; off >>= 1)
            acc += __shfl_xor(acc, off, 64);

        if (lane == 0)
            logits[obase + row0 + r] = acc;
    }
}

// One block per softmax row (2 blocks x 1024 threads, 8 elements/thread).
__global__ __launch_bounds__(1024) void softmax_kernel(
    const float* __restrict__ logits, float* __restrict__ out)
{
    const int r = blockIdx.x;   // 0 or 1
    const int t = threadIdx.x;  // 0 .. 1023
    const float* __restrict__ x = logits + (size_t)r * SS;

    float v[8];
    float m = -INFINITY;
    #pragma unroll
    for (int i = 0; i < 8; ++i) {
        v[i] = x[t + i * 1024];
        m = fmaxf(m, v[i]);
    }

    __shared__ float red[16];

    #pragma unroll
    for (int off = 32; off > 0; off >>= 1)
        m = fmaxf(m, __shfl_xor(m, off, 64));
    if ((t & 63) == 0) red[t >> 6] = m;
    __syncthreads();
    if (t < 64) {
        float mm = (t < 16) ? red[t] : -INFINITY;
        #pragma unroll
        for (int off = 8; off > 0; off >>= 1)
            mm = fmaxf(mm, __shfl_xor(mm, off, 64));
        if (t == 0) red[0] = mm;
    }
    __syncthreads();
    m = red[0];
    __syncthreads();   // red[] reused below

    float s = 0.f;
    #pragma unroll
    for (int i = 0; i < 8; ++i) {
        v[i] = expf(v[i] - m);
        s += v[i];
    }
    #pragma unroll
    for (int off = 32; off > 0; off >>= 1)
        s += __shfl_xor(s, off, 64);
    if ((t & 63) == 0) red[t >> 6] = s;
    __syncthreads();
    if (t < 64) {
        float ss = (t < 16) ? red[t] : 0.f;
        #pragma unroll
        for (int off = 8; off > 0; off >>= 1)
            ss += __shfl_xor(ss, off, 64);
        if (t == 0) red[0] = ss;
    }
    __syncthreads();
    const float inv = 1.0f / red[0];

    #pragma unroll
    for (int i = 0; i < 8; ++i)
        out[(size_t)r * SS + t + i * 1024] = v[i] * inv;
}

extern "C" void kernel_launch(void* const* d_in, const int* in_sizes, int n_in,
                              void* d_out, int out_size, void* d_ws, size_t ws_size,
                              hipStream_t stream) {
    const float* G1  = (const float*)d_in[0];
    const float* G2  = (const float*)d_in[1];
    const float* wp1 = (const float*)d_in[2];
    const float* wp2 = (const float*)d_in[3];
    float* out    = (float*)d_out;
    float* logits = (float*)d_ws;   // 2*SS floats = 64 KiB scratch

    gemv_kernel<<<(2 * SS) / (RPW * WPB), 256, 0, stream>>>(G1, G2, wp1, wp2, logits);
    softmax_kernel<<<2, 1024, 0, stream>>>(logits, out);
}

// Round 9
// 280.011 us; speedup vs baseline: 1.0141x; 1.0141x over previous
//
#include <hip/hip_runtime.h>

#define DD 4096
#define SS 8192
#define NRB 8                       // rows per block
#define NBLK ((2 * SS) / NRB)       // 2048 blocks, 8 per CU

// Block = 256 threads (4 waves) handles 8 consecutive rows of ONE matrix.
// wp row staged to LDS once per block (16 KiB); G streamed via float4 with
// 8 independent loads in flight; wp read from LDS (lgkm pipe, no vmem drain).
__global__ __launch_bounds__(256, 8) void gemv_kernel(
    const float* __restrict__ G1, const float* __restrict__ G2,
    const float* __restrict__ wp1, const float* __restrict__ wp2,
    float* __restrict__ logits)
{
    __shared__ float4 wlds[DD / 4];   // 16 KiB

    const int t   = threadIdx.x;
    const int b   = blockIdx.x;
    const int mat = b >> 10;                  // 1024 blocks per matrix
    const int rb  = (b & 1023) * NRB;

    const float*  G  = mat ? G2 : G1;
    const float4* W4 = reinterpret_cast<const float4*>(mat ? wp2 : wp1);

    #pragma unroll
    for (int k = 0; k < 4; ++k)
        wlds[k * 256 + t] = W4[k * 256 + t];
    __syncthreads();

    const int wid  = t >> 6;
    const int lane = t & 63;

    #pragma unroll
    for (int rr = 0; rr < 2; ++rr) {
        const int row = rb + wid * 2 + rr;
        const float4* __restrict__ Grow =
            reinterpret_cast<const float4*>(G + (size_t)row * DD);

        float a0 = 0.f, a1 = 0.f, a2 = 0.f, a3 = 0.f;
        #pragma unroll
        for (int c = 0; c < 2; ++c) {
            // 8 independent global loads in flight
            float4 g0 = Grow[c * 512 +   0 + lane];
            float4 g1 = Grow[c * 512 +  64 + lane];
            float4 g2 = Grow[c * 512 + 128 + lane];
            float4 g3 = Grow[c * 512 + 192 + lane];
            float4 g4 = Grow[c * 512 + 256 + lane];
            float4 g5 = Grow[c * 512 + 320 + lane];
            float4 g6 = Grow[c * 512 + 384 + lane];
            float4 g7 = Grow[c * 512 + 448 + lane];
            // wp from LDS (separate lgkm counter)
            float4 w0 = wlds[c * 512 +   0 + lane];
            float4 w1 = wlds[c * 512 +  64 + lane];
            float4 w2 = wlds[c * 512 + 128 + lane];
            float4 w3 = wlds[c * 512 + 192 + lane];
            float4 w4 = wlds[c * 512 + 256 + lane];
            float4 w5 = wlds[c * 512 + 320 + lane];
            float4 w6 = wlds[c * 512 + 384 + lane];
            float4 w7 = wlds[c * 512 + 448 + lane];
            a0 = fmaf(g0.x, w0.x, a0); a0 = fmaf(g0.y, w0.y, a0);
            a0 = fmaf(g0.z, w0.z, a0); a0 = fmaf(g0.w, w0.w, a0);
            a1 = fmaf(g1.x, w1.x, a1); a1 = fmaf(g1.y, w1.y, a1);
            a1 = fmaf(g1.z, w1.z, a1); a1 = fmaf(g1.w, w1.w, a1);
            a2 = fmaf(g2.x, w2.x, a2); a2 = fmaf(g2.y, w2.y, a2);
            a2 = fmaf(g2.z, w2.z, a2); a2 = fmaf(g2.w, w2.w, a2);
            a3 = fmaf(g3.x, w3.x, a3); a3 = fmaf(g3.y, w3.y, a3);
            a3 = fmaf(g3.z, w3.z, a3); a3 = fmaf(g3.w, w3.w, a3);
            a0 = fmaf(g4.x, w4.x, a0); a0 = fmaf(g4.y, w4.y, a0);
            a0 = fmaf(g4.z, w4.z, a0); a0 = fmaf(g4.w, w4.w, a0);
            a1 = fmaf(g5.x, w5.x, a1); a1 = fmaf(g5.y, w5.y, a1);
            a1 = fmaf(g5.z, w5.z, a1); a1 = fmaf(g5.w, w5.w, a1);
            a2 = fmaf(g6.x, w6.x, a2); a2 = fmaf(g6.y, w6.y, a2);
            a2 = fmaf(g6.z, w6.z, a2); a2 = fmaf(g6.w, w6.w, a2);
            a3 = fmaf(g7.x, w7.x, a3); a3 = fmaf(g7.y, w7.y, a3);
            a3 = fmaf(g7.z, w7.z, a3); a3 = fmaf(g7.w, w7.w, a3);
        }
        float acc = (a0 + a1) + (a2 + a3);

        #pragma unroll
        for (int off = 32; off > 0; off >>= 1)
            acc += __shfl_xor(acc, off, 64);

        if (lane == 0)
            logits[mat * SS + row] = acc;
    }
}

// One block per softmax row (2 blocks x 1024 threads, 8 elements/thread).
__global__ __launch_bounds__(1024) void softmax_kernel(
    const float* __restrict__ logits, float* __restrict__ out)
{
    const int r = blockIdx.x;
    const int t = threadIdx.x;
    const float* __restrict__ x = logits + (size_t)r * SS;

    float v[8];
    float m = -INFINITY;
    #pragma unroll
    for (int i = 0; i < 8; ++i) {
        v[i] = x[t + i * 1024];
        m = fmaxf(m, v[i]);
    }

    __shared__ float red[16];

    #pragma unroll
    for (int off = 32; off > 0; off >>= 1)
        m = fmaxf(m, __shfl_xor(m, off, 64));
    if ((t & 63) == 0) red[t >> 6] = m;
    __syncthreads();
    if (t < 64) {
        float mm = (t < 16) ? red[t] : -INFINITY;
        #pragma unroll
        for (int off = 8; off > 0; off >>= 1)
            mm = fmaxf(mm, __shfl_xor(mm, off, 64));
        if (t == 0) red[0] = mm;
    }
    __syncthreads();
    m = red[0];
    __syncthreads();

    float s = 0.f;
    #pragma unroll
    for (int i = 0; i < 8; ++i) {
        v[i] = expf(v[i] - m);
        s += v[i];
    }
    #pragma unroll
    for (int off = 32; off > 0; off >>= 1)
        s += __shfl_xor(s, off, 64);
    if ((t & 63) == 0) red[t >> 6] = s;
    __syncthreads();
    if (t < 64) {
        float ss = (t < 16) ? red[t] : 0.f;
        #pragma unroll
        for (int off = 8; off > 0; off >>= 1)
            ss += __shfl_xor(ss, off, 64);
        if (t == 0) red[0] = ss;
    }
    __syncthreads();
    const float inv = 1.0f / red[0];

    #pragma unroll
    for (int i = 0; i < 8; ++i)
        out[(size_t)r * SS + t + i * 1024] = v[i] * inv;
}

extern "C" void kernel_launch(void* const* d_in, const int* in_sizes, int n_in,
                              void* d_out, int out_size, void* d_ws, size_t ws_size,
                              hipStream_t stream) {
    const float* G1  = (const float*)d_in[0];
    const float* G2  = (const float*)d_in[1];
    const float* wp1 = (const float*)d_in[2];
    const float* wp2 = (const float*)d_in[3];
    float* out    = (float*)d_out;
    float* logits = (float*)d_ws;   // 2*SS floats = 64 KiB scratch

    gemv_kernel<<<NBLK, 256, 0, stream>>>(G1, G2, wp1, wp2, logits);
    softmax_kernel<<<2, 1024, 0, stream>>>(logits, out);
}

// Round 10
// 279.641 us; speedup vs baseline: 1.0154x; 1.0013x over previous
//
#include <hip/hip_runtime.h>

#define DD 4096
#define SS 8192
#define NRB 8                       // rows per block
#define NBLK ((2 * SS) / NRB)       // 2048 blocks

// Block = 256 threads (4 waves), 8 rows of one matrix per block, 2 rows/wave.
// wp staged to LDS once per block. Per row: two explicit register batches of
// 8 float4 G-loads (16 outstanding at peak); consuming ga waits vmcnt(8) so
// gb stays in flight under the FMA phase. launch_bounds(256,4) -> 128 VGPR
// budget so the batches actually live in registers.
__global__ __launch_bounds__(256, 4) void gemv_kernel(
    const float* __restrict__ G1, const float* __restrict__ G2,
    const float* __restrict__ wp1, const float* __restrict__ wp2,
    float* __restrict__ logits)
{
    __shared__ float4 wlds[DD / 4];   // 16 KiB

    const int t   = threadIdx.x;
    const int b   = blockIdx.x;
    const int mat = b >> 10;                  // 1024 blocks per matrix
    const int rb  = (b & 1023) * NRB;

    const float*  G  = mat ? G2 : G1;
    const float4* W4 = reinterpret_cast<const float4*>(mat ? wp2 : wp1);

    #pragma unroll
    for (int k = 0; k < 4; ++k)
        wlds[k * 256 + t] = W4[k * 256 + t];
    __syncthreads();

    const int wid  = t >> 6;
    const int lane = t & 63;

    #pragma unroll
    for (int rr = 0; rr < 2; ++rr) {
        const int row = rb + wid * 2 + rr;
        const float4* __restrict__ Grow =
            reinterpret_cast<const float4*>(G + (size_t)row * DD);

        // Phase 1: issue 16 independent global loads, no consumers in between.
        float4 ga[8], gb[8];
        #pragma unroll
        for (int i = 0; i < 8; ++i)
            ga[i] = Grow[i * 64 + lane];
        #pragma unroll
        for (int i = 0; i < 8; ++i)
            gb[i] = Grow[512 + i * 64 + lane];

        // Phase 2: consume ga (vmcnt(8) — gb still in flight).
        float a0 = 0.f, a1 = 0.f, a2 = 0.f, a3 = 0.f;
        #pragma unroll
        for (int i = 0; i < 8; i += 4) {
            float4 w0 = wlds[(i + 0) * 64 + lane];
            float4 w1 = wlds[(i + 1) * 64 + lane];
            float4 w2 = wlds[(i + 2) * 64 + lane];
            float4 w3 = wlds[(i + 3) * 64 + lane];
            a0 = fmaf(ga[i+0].x, w0.x, a0); a0 = fmaf(ga[i+0].y, w0.y, a0);
            a0 = fmaf(ga[i+0].z, w0.z, a0); a0 = fmaf(ga[i+0].w, w0.w, a0);
            a1 = fmaf(ga[i+1].x, w1.x, a1); a1 = fmaf(ga[i+1].y, w1.y, a1);
            a1 = fmaf(ga[i+1].z, w1.z, a1); a1 = fmaf(ga[i+1].w, w1.w, a1);
            a2 = fmaf(ga[i+2].x, w2.x, a2); a2 = fmaf(ga[i+2].y, w2.y, a2);
            a2 = fmaf(ga[i+2].z, w2.z, a2); a2 = fmaf(ga[i+2].w, w2.w, a2);
            a3 = fmaf(ga[i+3].x, w3.x, a3); a3 = fmaf(ga[i+3].y, w3.y, a3);
            a3 = fmaf(ga[i+3].z, w3.z, a3); a3 = fmaf(ga[i+3].w, w3.w, a3);
        }
        // Phase 3: consume gb (vmcnt(0)).
        #pragma unroll
        for (int i = 0; i < 8; i += 4) {
            float4 w0 = wlds[512 + (i + 0) * 64 + lane];
            float4 w1 = wlds[512 + (i + 1) * 64 + lane];
            float4 w2 = wlds[512 + (i + 2) * 64 + lane];
            float4 w3 = wlds[512 + (i + 3) * 64 + lane];
            a0 = fmaf(gb[i+0].x, w0.x, a0); a0 = fmaf(gb[i+0].y, w0.y, a0);
            a0 = fmaf(gb[i+0].z, w0.z, a0); a0 = fmaf(gb[i+0].w, w0.w, a0);
            a1 = fmaf(gb[i+1].x, w1.x, a1); a1 = fmaf(gb[i+1].y, w1.y, a1);
            a1 = fmaf(gb[i+1].z, w1.z, a1); a1 = fmaf(gb[i+1].w, w1.w, a1);
            a2 = fmaf(gb[i+2].x, w2.x, a2); a2 = fmaf(gb[i+2].y, w2.y, a2);
            a2 = fmaf(gb[i+2].z, w2.z, a2); a2 = fmaf(gb[i+2].w, w2.w, a2);
            a3 = fmaf(gb[i+3].x, w3.x, a3); a3 = fmaf(gb[i+3].y, w3.y, a3);
            a3 = fmaf(gb[i+3].z, w3.z, a3); a3 = fmaf(gb[i+3].w, w3.w, a3);
        }

        float acc = (a0 + a1) + (a2 + a3);

        #pragma unroll
        for (int off = 32; off > 0; off >>= 1)
            acc += __shfl_xor(acc, off, 64);

        if (lane == 0)
            logits[mat * SS + row] = acc;
    }
}

// One block per softmax row (2 blocks x 1024 threads, 8 elements/thread).
__global__ __launch_bounds__(1024) void softmax_kernel(
    const float* __restrict__ logits, float* __restrict__ out)
{
    const int r = blockIdx.x;
    const int t = threadIdx.x;
    const float* __restrict__ x = logits + (size_t)r * SS;

    float v[8];
    float m = -INFINITY;
    #pragma unroll
    for (int i = 0; i < 8; ++i) {
        v[i] = x[t + i * 1024];
        m = fmaxf(m, v[i]);
    }

    __shared__ float red[16];

    #pragma unroll
    for (int off = 32; off > 0; off >>= 1)
        m = fmaxf(m, __shfl_xor(m, off, 64));
    if ((t & 63) == 0) red[t >> 6] = m;
    __syncthreads();
    if (t < 64) {
        float mm = (t < 16) ? red[t] : -INFINITY;
        #pragma unroll
        for (int off = 8; off > 0; off >>= 1)
            mm = fmaxf(mm, __shfl_xor(mm, off, 64));
        if (t == 0) red[0] = mm;
    }
    __syncthreads();
    m = red[0];
    __syncthreads();

    float s = 0.f;
    #pragma unroll
    for (int i = 0; i < 8; ++i) {
        v[i] = expf(v[i] - m);
        s += v[i];
    }
    #pragma unroll
    for (int off = 32; off > 0; off >>= 1)
        s += __shfl_xor(s, off, 64);
    if ((t & 63) == 0) red[t >> 6] = s;
    __syncthreads();
    if (t < 64) {
        float ss = (t < 16) ? red[t] : 0.f;
        #pragma unroll
        for (int off = 8; off > 0; off >>= 1)
            ss += __shfl_xor(ss, off, 64);
        if (t == 0) red[0] = ss;
    }
    __syncthreads();
    const float inv = 1.0f / red[0];

    #pragma unroll
    for (int i = 0; i < 8; ++i)
        out[(size_t)r * SS + t + i * 1024] = v[i] * inv;
}

extern "C" void kernel_launch(void* const* d_in, const int* in_sizes, int n_in,
                              void* d_out, int out_size, void* d_ws, size_t ws_size,
                              hipStream_t stream) {
    const float* G1  = (const float*)d_in[0];
    const float* G2  = (const float*)d_in[1];
    const float* wp1 = (const float*)d_in[2];
    const float* wp2 = (const float*)d_in[3];
    float* out    = (float*)d_out;
    float* logits = (float*)d_ws;   // 2*SS floats = 64 KiB scratch

    gemv_kernel<<<NBLK, 256, 0, stream>>>(G1, G2, wp1, wp2, logits);
    softmax_kernel<<<2, 1024, 0, stream>>>(logits, out);
}